// Round 3
// baseline (24400.803 us; speedup 1.0000x reference)
//
#include <hip/hip_runtime.h>
#include <hip/hip_bf16.h>
#include <hip/hip_cooperative_groups.h>
#include <math.h>

namespace cg = cooperative_groups;

// Problem dims
#define BB 64
#define TT 128
#define T1 127
#define OBS 512
#define HH 1024
#define LL 32
#define CC 32
#define AA 18
#define KIN 1042   // LC + A
#define G3 3072    // 3*H

__device__ __forceinline__ float4 ld4(const float* p) { return *(const float4*)p; }

// ---------------- transpose wih (3072 x 1042) -> wihT (1042 x 3072) ----------------
__global__ __launch_bounds__(256) void tr_k(const float* __restrict__ wih, float* __restrict__ wihT)
{
    __shared__ float tile[32][33];
    int g0 = blockIdx.x * 32;   // 96
    int k0 = blockIdx.y * 32;   // 33 (covers 1056, guard 1042)
    int tx = threadIdx.x, ty = threadIdx.y; // 32 x 8
    #pragma unroll
    for (int r = 0; r < 32; r += 8) {
        int g = g0 + ty + r, k = k0 + tx;
        tile[ty + r][tx] = (k < KIN) ? wih[(size_t)g * KIN + k] : 0.f;
    }
    __syncthreads();
    #pragma unroll
    for (int r = 0; r < 32; r += 8) {
        int k = k0 + ty + r, g = g0 + tx;
        if (k < KIN) wihT[(size_t)k * G3 + g] = tile[tx][ty + r];
    }
}

// ---------------- fp32 GEMM: C = A(MxK) @ B(KxN) + bias (+extra) (relu) --------------
// tile 128x128, 256 threads, 8x8 micro, ktile 16, register-prefetch double buffer
template<int RELU, int HAS_EXTRA, int AAL>
__global__ __launch_bounds__(256) void gemm_k(const float* __restrict__ A, const float* __restrict__ Bm,
    float* __restrict__ Cm, int M, int N, int K,
    const float* __restrict__ bias, const float* __restrict__ extra)
{
    __shared__ float As[16][132];
    __shared__ float Bs[16][132];
    int tid = threadIdx.x;
    int tx = tid & 15, ty = tid >> 4;
    int m0 = blockIdx.y * 128, n0 = blockIdx.x * 128;
    float acc[8][8];
    #pragma unroll
    for (int i = 0; i < 8; ++i)
        #pragma unroll
        for (int j = 0; j < 8; ++j) acc[i][j] = 0.f;

    int arow = tid >> 1;
    int ak0  = (tid & 1) * 8;   // k offset 0 or 8
    int am   = m0 + arow;

    float  ar[8];
    float4 br[2];

    auto loadA = [&](int kt) {
        if (am < M) {
            const float* ap = A + (size_t)am * K + kt + ak0;
            if (AAL) {
                float4 v0 = ld4(ap), v1 = ld4(ap + 4);
                ar[0] = v0.x; ar[1] = v0.y; ar[2] = v0.z; ar[3] = v0.w;
                ar[4] = v1.x; ar[5] = v1.y; ar[6] = v1.z; ar[7] = v1.w;
            } else {
                #pragma unroll
                for (int e = 0; e < 8; ++e) ar[e] = ap[e];
            }
        } else {
            #pragma unroll
            for (int e = 0; e < 8; ++e) ar[e] = 0.f;
        }
    };
    auto loadB = [&](int kt) {
        #pragma unroll
        for (int i2 = 0; i2 < 2; ++i2) {
            int idx = tid * 2 + i2;         // 0..511
            int kk = idx >> 5, c4 = idx & 31;
            br[i2] = ld4(Bm + (size_t)(kt + kk) * N + n0 + c4 * 4);
        }
    };

    loadA(0); loadB(0);

    for (int kt = 0; kt < K; kt += 16) {
        // write prefetched regs -> LDS
        #pragma unroll
        for (int e = 0; e < 8; ++e) As[ak0 + e][arow] = ar[e];
        #pragma unroll
        for (int i2 = 0; i2 < 2; ++i2) {
            int idx = tid * 2 + i2;
            int kk = idx >> 5, c4 = idx & 31;
            *(float4*)&Bs[kk][c4 * 4] = br[i2];
        }
        __syncthreads();
        if (kt + 16 < K) { loadA(kt + 16); loadB(kt + 16); }
        #pragma unroll
        for (int k = 0; k < 16; ++k) {
            float av[8], bv[8];
            *(float4*)&av[0] = *(const float4*)&As[k][ty * 8];
            *(float4*)&av[4] = *(const float4*)&As[k][ty * 8 + 4];
            *(float4*)&bv[0] = *(const float4*)&Bs[k][tx * 8];
            *(float4*)&bv[4] = *(const float4*)&Bs[k][tx * 8 + 4];
            #pragma unroll
            for (int i = 0; i < 8; ++i)
                #pragma unroll
                for (int j = 0; j < 8; ++j)
                    acc[i][j] = fmaf(av[i], bv[j], acc[i][j]);
        }
        __syncthreads();
    }
    #pragma unroll
    for (int i = 0; i < 8; ++i) {
        int m = m0 + ty * 8 + i;
        if (m >= M) break;
        #pragma unroll
        for (int jh = 0; jh < 2; ++jh) {
            int n = n0 + tx * 8 + jh * 4;
            float4 v;
            v.x = acc[i][jh * 4 + 0] + bias[n + 0];
            v.y = acc[i][jh * 4 + 1] + bias[n + 1];
            v.z = acc[i][jh * 4 + 2] + bias[n + 2];
            v.w = acc[i][jh * 4 + 3] + bias[n + 3];
            if (HAS_EXTRA) {
                float4 e = ld4(extra + (size_t)m * N + n);
                v.x += e.x; v.y += e.y; v.z += e.z; v.w += e.w;
            }
            if (RELU) {
                v.x = fmaxf(v.x, 0.f); v.y = fmaxf(v.y, 0.f);
                v.z = fmaxf(v.z, 0.f); v.w = fmaxf(v.w, 0.f);
            }
            *(float4*)(Cm + (size_t)m * N + n) = v;
        }
    }
}

// ---------------- step-0 sampling: argmax(epost[:,0] + gumbel[0]) ----------------
__global__ __launch_bounds__(256) void samp0_k(const float* __restrict__ epost, const float* __restrict__ gumbel,
                                               float* __restrict__ samples_out, int* __restrict__ sidx)
{
    int b = blockIdx.x;
    int tid = threadIdx.x;
    int l = tid >> 3, s = tid & 7;
    const float* lg = epost + ((size_t)b * TT + 0) * HH + l * 32;
    const float* gm = gumbel + (((size_t)0 * BB + b) * LL + l) * CC;
    float u[4];
    #pragma unroll
    for (int i = 0; i < 4; ++i) { int c = s * 4 + i; u[i] = lg[c] + gm[c]; }
    float best = u[0]; int bi = s * 4;
    #pragma unroll
    for (int i = 1; i < 4; ++i) { if (u[i] > best) { best = u[i]; bi = s * 4 + i; } }
    for (int m = 1; m < 8; m <<= 1) {
        float ov = __shfl_xor(best, m, 8);
        int   oi = __shfl_xor(bi, m, 8);
        if (ov > best || (ov == best && oi < bi)) { best = ov; bi = oi; }
    }
    float* so = samples_out + ((size_t)b * T1 + 0) * HH + l * 32;
    #pragma unroll
    for (int i = 0; i < 4; ++i) { int c = s * 4 + i; so[c] = (c == bi) ? 1.f : 0.f; }
    if (s == 0) sidx[((size_t)0 * BB + b) * LL + l] = bi;
}

// ---------------- persistent cooperative scan kernel ----------------
// 256 blocks x 512 threads, 1 block/CU (LDS 126.6 KiB). Two grid.sync per step.
// Phase A (GRU): block owns 4 output columns j0..j0+3, all 64 batches, K split
//   across two 256-thread halves (kh). whh slice staged in LDS once for all steps.
// Phase B (logits+sample): block = (b-chunk of 8, latent l), K split across kh.
__global__ __launch_bounds__(512) void scan_k(
    float* __restrict__ hbuf, float* __restrict__ hso,
    const float* __restrict__ wihT, const float* __restrict__ whh,
    const float* __restrict__ bih, const float* __restrict__ bhh,
    int* __restrict__ sidx, const int* __restrict__ act,
    const float* __restrict__ postw, const float* __restrict__ epost,
    const float* __restrict__ gum, float* __restrict__ plog,
    float* __restrict__ smo)
{
    cg::grid_group grid = cg::this_grid();
    __shared__ __align__(16) char smraw[129664];
    // persistent whh stage: [2][12][516] floats = 49,536 B
    float (*wfull)[12][516] = (float(*)[12][516])smraw;
    char* U = smraw + 49536;
    // phase A views (80,128 B)
    float (*h_s)[64][132] = (float(*)[64][132])U;          // 67,584
    int   (*off_s)[33]    = (int(*)[33])(U + 67584);       //  8,448
    float (*ps)[4]        = (float(*)[4])(U + 76032);      //  4,096
    // phase B views (43,264 B)
    float (*hb_s)[8][132]  = (float(*)[8][132])U;          //  8,448
    float (*wb_s)[32][132] = (float(*)[32][132])(U + 8448);// 33,792
    float* psb             = (float*)(U + 42240);          //  1,024

    int tid = threadIdx.x;
    int kh = tid >> 8;              // K-half 0/1
    int r  = tid & 255;
    int bid = blockIdx.x;
    // phase A ids
    int sb = (bid & 7) * 32 + (bid >> 3);
    int j0 = sb * 4;
    int ab = r >> 2, q = r & 3, j = j0 + q;
    // phase B ids
    int l  = bid & 31;
    int bc = bid >> 5;
    int b0 = bc * 8;
    int b8 = r >> 5;
    int c  = r & 31;
    int n0 = l * 32;

    // stage whh once: rows rr=gate*4+qq -> whh[gate*1024 + j0 + qq][:]
    for (int i = tid; i < 3072; i += 512) {
        int k4 = i & 127;
        int rowi = i >> 7;          // 0..23
        int kh2 = (rowi >= 12) ? 1 : 0;
        int rr = rowi - kh2 * 12;
        int g = (rr >> 2) * 1024 + j0 + (rr & 3);
        *(float4*)&wfull[kh2][rr][k4 * 4] = ld4(whh + (size_t)g * HH + kh2 * 512 + k4 * 4);
    }
    __syncthreads();

    const int kbase = kh * 512;

    for (int t = 1; t <= 127; ++t) {
        // ================= phase A: h_t = GRU(h_{t-1}, [samp_{t-1}, a_{t-1}]) =========
        {
            const float* hprev = hbuf + ((t - 1) & 1) * 65536;
            float* hnew = hbuf + (t & 1) * 65536;
            const int* sidx_prev = sidx + (size_t)(t - 1) * 2048;

            for (int i = tid; i < 64 * 33; i += 512) {
                int bb = i / 33, ll = i - bb * 33;
                off_s[bb][ll] = (ll < 32) ? (ll * 32 + sidx_prev[bb * 32 + ll])
                                          : (1024 + act[bb * TT + (t - 1)]);
            }
            __syncthreads();

            // gather partials (one-hot rows of wihT); n-gate gather (g2) kept
            // separate from h-dot (a2): n = tanh(inn + r*hn)
            float a0 = 0.f, a1 = 0.f, a2 = 0.f, g2 = 0.f;
            if (kh == 0) {
                #pragma unroll
                for (int i = 0; i < 17; ++i) {
                    int o = off_s[ab][i];
                    const float* wp = wihT + (size_t)o * G3 + j;
                    a0 += wp[0]; a1 += wp[1024]; g2 += wp[2048];
                }
            } else {
                #pragma unroll
                for (int i = 17; i < 33; ++i) {
                    int o = off_s[ab][i];
                    const float* wp = wihT + (size_t)o * G3 + j;
                    a0 += wp[0]; a1 += wp[1024]; g2 += wp[2048];
                }
            }

            // h dots over this K-half, register-prefetched h staging
            float4 hreg[8];
            auto loadH = [&](int kc) {
                #pragma unroll
                for (int m = 0; m < 8; ++m) {
                    int i = r + m * 256;
                    int row = i >> 5, c4 = i & 31;
                    hreg[m] = ld4(hprev + row * HH + kbase + kc * 128 + c4 * 4);
                }
            };
            loadH(0);
            for (int kc = 0; kc < 4; ++kc) {
                #pragma unroll
                for (int m = 0; m < 8; ++m) {
                    int i = r + m * 256;
                    int row = i >> 5, c4 = i & 31;
                    *(float4*)&h_s[kh][row][c4 * 4] = hreg[m];
                }
                __syncthreads();
                if (kc < 3) loadH(kc + 1);
                #pragma unroll 8
                for (int k4 = 0; k4 < 32; ++k4) {
                    float4 hv = *(const float4*)&h_s[kh][ab][k4 * 4];
                    float4 w0 = *(const float4*)&wfull[kh][q][kc * 128 + k4 * 4];
                    float4 w1 = *(const float4*)&wfull[kh][4 + q][kc * 128 + k4 * 4];
                    float4 w2 = *(const float4*)&wfull[kh][8 + q][kc * 128 + k4 * 4];
                    a0 += hv.x * w0.x + hv.y * w0.y + hv.z * w0.z + hv.w * w0.w;
                    a1 += hv.x * w1.x + hv.y * w1.y + hv.z * w1.z + hv.w * w1.w;
                    a2 += hv.x * w2.x + hv.y * w2.y + hv.z * w2.z + hv.w * w2.w;
                }
                __syncthreads();
            }
            if (kh == 1) { ps[r][0] = a0; ps[r][1] = a1; ps[r][2] = a2; ps[r][3] = g2; }
            __syncthreads();
            if (kh == 0) {
                float s0 = a0 + ps[r][0];
                float s1 = a1 + ps[r][1];
                float hn = a2 + ps[r][2] + bhh[2048 + j];
                float inn = g2 + ps[r][3] + bih[2048 + j];
                float rr = 1.f / (1.f + expf(-(s0 + bih[j] + bhh[j])));
                float zz = 1.f / (1.f + expf(-(s1 + bih[1024 + j] + bhh[1024 + j])));
                float nn = tanhf(inn + rr * hn);
                float hp = hprev[ab * HH + j];
                float hv = (1.f - zz) * nn + zz * hp;
                hnew[ab * HH + j] = hv;
                hso[((size_t)ab * T1 + (t - 1)) * HH + j] = hv;
            }
        }
        __threadfence();
        grid.sync();

        // ================= phase B: logits_t = h_t @ postw_top + epost[:,t]; sample ==
        {
            const float* hcur = hbuf + (t & 1) * 65536;
            float acc = 0.f;
            for (int kc = 0; kc < 4; ++kc) {
                int kb = kbase + kc * 128;
                {
                    int row = r >> 5, c4 = r & 31;
                    *(float4*)&hb_s[kh][row][c4 * 4] = ld4(hcur + (b0 + row) * HH + kb + c4 * 4);
                }
                for (int i = r; i < 4096; i += 256) {
                    int k = i >> 5, cc = i & 31;
                    wb_s[kh][cc][k] = postw[(size_t)(kb + k) * HH + n0 + cc];
                }
                __syncthreads();
                #pragma unroll 8
                for (int k4 = 0; k4 < 32; ++k4) {
                    float4 hv = *(const float4*)&hb_s[kh][b8][k4 * 4];
                    float4 wv = *(const float4*)&wb_s[kh][c][k4 * 4];
                    acc += hv.x * wv.x + hv.y * wv.y + hv.z * wv.z + hv.w * wv.w;
                }
                __syncthreads();
            }
            if (kh == 1) psb[r] = acc;
            __syncthreads();
            if (kh == 0) {
                int b = b0 + b8;
                int n = n0 + c;
                float lg = acc + psb[r] + epost[((size_t)b * TT + t) * HH + n];
                plog[((size_t)(t - 1) * BB + b) * HH + n] = lg;
                if (t <= 126) {
                    float u = lg + gum[(((size_t)t * BB + b) * LL + l) * CC + c];
                    float best = u; int bi = c;
                    for (int m = 1; m < 32; m <<= 1) {
                        float ov = __shfl_xor(best, m, 32);
                        int   oi = __shfl_xor(bi, m, 32);
                        if (ov > best || (ov == best && oi < bi)) { best = ov; bi = oi; }
                    }
                    smo[((size_t)b * T1 + t) * HH + n] = (c == bi) ? 1.f : 0.f;
                    if (c == 0) sidx[((size_t)t * BB + b) * LL + l] = bi;
                }
            }
        }
        __threadfence();
        grid.sync();
    }
}

// ---------------- KL reduction ----------------
__global__ __launch_bounds__(256) void kl_k(const float* __restrict__ prior,
    const float* __restrict__ plog, float* __restrict__ out)
{
    int rrow = blockIdx.x;              // b*127 + i
    int b = rrow / T1, i = rrow - b * T1;
    int tid = threadIdx.x;
    int l = tid >> 3, s = tid & 7;
    const float* pp = prior + (size_t)rrow * HH + l * 32;
    const float* qq = plog + ((size_t)i * BB + b) * HH + l * 32;
    float pv[4], qv[4];
    #pragma unroll
    for (int e = 0; e < 4; ++e) { int c = s * 4 + e; pv[e] = pp[c]; qv[e] = qq[c]; }
    float mp = fmaxf(fmaxf(pv[0], pv[1]), fmaxf(pv[2], pv[3]));
    float mq = fmaxf(fmaxf(qv[0], qv[1]), fmaxf(qv[2], qv[3]));
    for (int m = 1; m < 8; m <<= 1) {
        mp = fmaxf(mp, __shfl_xor(mp, m, 8));
        mq = fmaxf(mq, __shfl_xor(mq, m, 8));
    }
    float sp = 0.f, sq = 0.f;
    #pragma unroll
    for (int e = 0; e < 4; ++e) { sp += expf(pv[e] - mp); sq += expf(qv[e] - mq); }
    for (int m = 1; m < 8; m <<= 1) { sp += __shfl_xor(sp, m, 8); sq += __shfl_xor(sq, m, 8); }
    float lsp = mp + logf(sp), lsq = mq + logf(sq);
    float kf = 0.f, kr = 0.f;
    #pragma unroll
    for (int e = 0; e < 4; ++e) {
        float lp = pv[e] - lsp, lq = qv[e] - lsq;
        float eq = expf(lq), ep = expf(lp);
        kf += eq * (lq - lp); kr += ep * (lp - lq);
    }
    for (int m = 1; m < 8; m <<= 1) { kf += __shfl_xor(kf, m, 8); kr += __shfl_xor(kr, m, 8); }
    __shared__ float kfs[32], krs[32];
    if (s == 0) { kfs[l] = kf; krs[l] = kr; }
    __syncthreads();
    if (tid == 0) {
        float f = 0.f, r = 0.f;
        for (int l2 = 0; l2 < 32; ++l2) { f += kfs[l2]; r += krs[l2]; }
        float val = fmaxf(0.8f * f + 0.2f * r, 1.0f);
        atomicAdd(out, val * (1.0f / 8128.0f));
    }
}

// ---------------- gather-sum of dec_w1 bottom rows per (b,i) ----------------
__global__ __launch_bounds__(256) void gsum_k(const float* __restrict__ dw1bot,
    const int* __restrict__ sidx, float* __restrict__ gsum)
{
    int rrow = blockIdx.x;              // b*127 + i
    int b = rrow / T1, i = rrow - b * T1;
    __shared__ int offs[32];
    int tid = threadIdx.x;
    if (tid < 32) offs[tid] = tid * 32 + sidx[((size_t)i * BB + b) * LL + tid];
    __syncthreads();
    int n = tid * 4;
    float4 acc = make_float4(0.f, 0.f, 0.f, 0.f);
    #pragma unroll 4
    for (int l = 0; l < 32; ++l) {
        float4 v = ld4(dw1bot + (size_t)offs[l] * HH + n);
        acc.x += v.x; acc.y += v.y; acc.z += v.z; acc.w += v.w;
    }
    *(float4*)(gsum + (size_t)rrow * HH + n) = acc;
}

// ---------------- reward head ----------------
__global__ __launch_bounds__(256) void rew_k(const float* __restrict__ hs, const float* __restrict__ reww,
    const float* __restrict__ rewb, const int* __restrict__ sidx, float* __restrict__ pred)
{
    int rrow = blockIdx.x * 4 + (threadIdx.x >> 6);
    int lane = threadIdx.x & 63;
    int b = rrow / T1, i = rrow - b * T1;
    const float* hp = hs + (size_t)rrow * HH;
    float acc = 0.f;
    for (int k = lane; k < HH; k += 64) acc += hp[k] * reww[k];
    for (int m = 1; m < 64; m <<= 1) acc += __shfl_xor(acc, m, 64);
    if (lane == 0) {
        float g = 0.f;
        const int* sp = sidx + ((size_t)i * BB + b) * LL;
        for (int l = 0; l < 32; ++l) g += reww[1024 + l * 32 + sp[l]];
        pred[rrow] = acc + g + rewb[0];
    }
}

extern "C" void kernel_launch(void* const* d_in, const int* in_sizes, int n_in,
                              void* d_out, int out_size, void* d_ws, size_t ws_size,
                              hipStream_t stream) {
    const float* obs   = (const float*)d_in[0];
    const float* gum   = (const float*)d_in[1];
    const float* ew1   = (const float*)d_in[2];
    const float* eb1   = (const float*)d_in[3];
    const float* ew2   = (const float*)d_in[4];
    const float* eb2   = (const float*)d_in[5];
    const float* wih   = (const float*)d_in[6];
    const float* whh   = (const float*)d_in[7];
    const float* bih   = (const float*)d_in[8];
    const float* bhh   = (const float*)d_in[9];
    const float* priw  = (const float*)d_in[10];
    const float* prib  = (const float*)d_in[11];
    const float* postw = (const float*)d_in[12];
    const float* postb = (const float*)d_in[13];
    const float* dw1   = (const float*)d_in[14];
    const float* db1   = (const float*)d_in[15];
    const float* dw2   = (const float*)d_in[16];
    const float* db2   = (const float*)d_in[17];
    const float* reww  = (const float*)d_in[18];
    const float* rewb  = (const float*)d_in[19];
    const int*   act   = (const int*)d_in[20];
    (void)in_sizes; (void)n_in; (void)out_size; (void)ws_size;

    float* ws = (float*)d_ws;
    float* wihT = ws;                       // 1042*3072 = 3,201,024
    float* bufA = wihT + 3201024;           // 8192*1024 : e1 -> epost -> prior_logits
    float* bufB = bufA + 8388608;           // 8192*1024 : e  -> dec_tmp
    float* plog = bufB + 8388608;           // 127*64*1024 : post_logits -> gsum
    float* hbuf = plog + 8323072;           // 2 * 64*1024
    int*   sidx = (int*)(hbuf + 2 * 65536); // 127*64*32 ints

    float* out = (float*)d_out;
    float* recon = out;                     // 8128*512
    float* pred  = out + 4161536;           // 8128
    float* klo   = pred + 8128;             // 1
    float* hso   = klo + 1;                 // 8128*1024 (NOT 16B-aligned: scalar/AAL=0 paths only)
    float* smo   = hso + 8323072;           // 8128*1024

    hipMemsetAsync(hbuf, 0, 65536 * sizeof(float), stream);
    hipMemsetAsync(klo, 0, sizeof(float), stream);

    tr_k<<<dim3(96, 33), dim3(32, 8), 0, stream>>>(wih, wihT);
    // encoder
    gemm_k<1,0,1><<<dim3(8, 64), 256, 0, stream>>>(obs,  ew1, bufA, 8192, 1024, 512,  eb1, nullptr);
    gemm_k<1,0,1><<<dim3(8, 64), 256, 0, stream>>>(bufA, ew2, bufB, 8192, 1024, 1024, eb2, nullptr);
    // epost = e @ post_w[1024:] + post_b  (hoisted e-half of posterior logits)
    gemm_k<0,0,1><<<dim3(8, 64), 256, 0, stream>>>(bufB, postw + 1024 * 1024, bufA, 8192, 1024, 1024, postb, nullptr);
    // step-0 sample
    samp0_k<<<64, 256, 0, stream>>>(bufA, gum, smo, sidx);

    // persistent cooperative scan (127 steps, 2 grid.syncs per step)
    {
        float* hbuf_p = hbuf; float* hso_p = hso;
        const float* wihT_p = wihT; const float* whh_p = whh;
        const float* bih_p = bih; const float* bhh_p = bhh;
        int* sidx_p = sidx; const int* act_p = act;
        const float* postw_p = postw; const float* epost_p = bufA;
        const float* gum_p = gum; float* plog_p = plog; float* smo_p = smo;
        void* args[] = { &hbuf_p, &hso_p, &wihT_p, &whh_p, &bih_p, &bhh_p,
                         &sidx_p, &act_p, &postw_p, &epost_p, &gum_p, &plog_p, &smo_p };
        hipLaunchCooperativeKernel((const void*)scan_k, dim3(256), dim3(512), args, 0, stream);
    }

    // prior logits (A=hso is not 16B-aligned -> AAL=0)
    gemm_k<0,0,0><<<dim3(8, 64), 256, 0, stream>>>(hso, priw, bufA, 8128, 1024, 1024, prib, nullptr);
    // KL
    kl_k<<<8128, 256, 0, stream>>>(bufA, plog, klo);
    // decoder: gather-sum then 2 GEMMs
    gsum_k<<<8128, 256, 0, stream>>>(dw1 + 1024 * 1024, sidx, plog);
    gemm_k<1,1,0><<<dim3(8, 64), 256, 0, stream>>>(hso, dw1, bufB, 8128, 1024, 1024, db1, plog);
    gemm_k<0,0,1><<<dim3(4, 64), 256, 0, stream>>>(bufB, dw2, recon, 8128, 512, 1024, db2, nullptr);
    // reward
    rew_k<<<2032, 256, 0, stream>>>(hso, reww, rewb, sidx, pred);
}

// Round 4
// 10853.259 us; speedup vs baseline: 2.2482x; 2.2482x over previous
//
#include <hip/hip_runtime.h>
#include <hip/hip_bf16.h>
#include <math.h>

// Problem dims
#define BB 64
#define TT 128
#define T1 127
#define OBS 512
#define HH 1024
#define LL 32
#define CC 32
#define AA 18
#define KIN 1042   // LC + A
#define G3 3072    // 3*H
#define NWG 256

__device__ __forceinline__ float4 ld4(const float* p) { return *(const float4*)p; }

// ---------------- transpose wih (3072 x 1042) -> wihT (1042 x 3072) ----------------
__global__ __launch_bounds__(256) void tr_k(const float* __restrict__ wih, float* __restrict__ wihT)
{
    __shared__ float tile[32][33];
    int g0 = blockIdx.x * 32;   // 96
    int k0 = blockIdx.y * 32;   // 33 (covers 1056, guard 1042)
    int tx = threadIdx.x, ty = threadIdx.y; // 32 x 8
    #pragma unroll
    for (int r = 0; r < 32; r += 8) {
        int g = g0 + ty + r, k = k0 + tx;
        tile[ty + r][tx] = (k < KIN) ? wih[(size_t)g * KIN + k] : 0.f;
    }
    __syncthreads();
    #pragma unroll
    for (int r = 0; r < 32; r += 8) {
        int k = k0 + ty + r, g = g0 + tx;
        if (k < KIN) wihT[(size_t)k * G3 + g] = tile[tx][ty + r];
    }
}

// ---------------- fp32 GEMM: C = A(MxK) @ B(KxN) + bias (+extra) (relu) --------------
// tile 128x128, 256 threads, 8x8 micro, ktile 16, register-prefetch double buffer
template<int RELU, int HAS_EXTRA, int AAL>
__global__ __launch_bounds__(256) void gemm_k(const float* __restrict__ A, const float* __restrict__ Bm,
    float* __restrict__ Cm, int M, int N, int K,
    const float* __restrict__ bias, const float* __restrict__ extra)
{
    __shared__ float As[16][132];
    __shared__ float Bs[16][132];
    int tid = threadIdx.x;
    int tx = tid & 15, ty = tid >> 4;
    int m0 = blockIdx.y * 128, n0 = blockIdx.x * 128;
    float acc[8][8];
    #pragma unroll
    for (int i = 0; i < 8; ++i)
        #pragma unroll
        for (int j = 0; j < 8; ++j) acc[i][j] = 0.f;

    int arow = tid >> 1;
    int ak0  = (tid & 1) * 8;   // k offset 0 or 8
    int am   = m0 + arow;

    float  ar[8];
    float4 br[2];

    auto loadA = [&](int kt) {
        if (am < M) {
            const float* ap = A + (size_t)am * K + kt + ak0;
            if (AAL) {
                float4 v0 = ld4(ap), v1 = ld4(ap + 4);
                ar[0] = v0.x; ar[1] = v0.y; ar[2] = v0.z; ar[3] = v0.w;
                ar[4] = v1.x; ar[5] = v1.y; ar[6] = v1.z; ar[7] = v1.w;
            } else {
                #pragma unroll
                for (int e = 0; e < 8; ++e) ar[e] = ap[e];
            }
        } else {
            #pragma unroll
            for (int e = 0; e < 8; ++e) ar[e] = 0.f;
        }
    };
    auto loadB = [&](int kt) {
        #pragma unroll
        for (int i2 = 0; i2 < 2; ++i2) {
            int idx = tid * 2 + i2;         // 0..511
            int kk = idx >> 5, c4 = idx & 31;
            br[i2] = ld4(Bm + (size_t)(kt + kk) * N + n0 + c4 * 4);
        }
    };

    loadA(0); loadB(0);

    for (int kt = 0; kt < K; kt += 16) {
        // write prefetched regs -> LDS
        #pragma unroll
        for (int e = 0; e < 8; ++e) As[ak0 + e][arow] = ar[e];
        #pragma unroll
        for (int i2 = 0; i2 < 2; ++i2) {
            int idx = tid * 2 + i2;
            int kk = idx >> 5, c4 = idx & 31;
            *(float4*)&Bs[kk][c4 * 4] = br[i2];
        }
        __syncthreads();
        if (kt + 16 < K) { loadA(kt + 16); loadB(kt + 16); }
        #pragma unroll
        for (int k = 0; k < 16; ++k) {
            float av[8], bv[8];
            *(float4*)&av[0] = *(const float4*)&As[k][ty * 8];
            *(float4*)&av[4] = *(const float4*)&As[k][ty * 8 + 4];
            *(float4*)&bv[0] = *(const float4*)&Bs[k][tx * 8];
            *(float4*)&bv[4] = *(const float4*)&Bs[k][tx * 8 + 4];
            #pragma unroll
            for (int i = 0; i < 8; ++i)
                #pragma unroll
                for (int j = 0; j < 8; ++j)
                    acc[i][j] = fmaf(av[i], bv[j], acc[i][j]);
        }
        __syncthreads();
    }
    #pragma unroll
    for (int i = 0; i < 8; ++i) {
        int m = m0 + ty * 8 + i;
        if (m >= M) break;
        #pragma unroll
        for (int jh = 0; jh < 2; ++jh) {
            int n = n0 + tx * 8 + jh * 4;
            float4 v;
            v.x = acc[i][jh * 4 + 0] + bias[n + 0];
            v.y = acc[i][jh * 4 + 1] + bias[n + 1];
            v.z = acc[i][jh * 4 + 2] + bias[n + 2];
            v.w = acc[i][jh * 4 + 3] + bias[n + 3];
            if (HAS_EXTRA) {
                float4 e = ld4(extra + (size_t)m * N + n);
                v.x += e.x; v.y += e.y; v.z += e.z; v.w += e.w;
            }
            if (RELU) {
                v.x = fmaxf(v.x, 0.f); v.y = fmaxf(v.y, 0.f);
                v.z = fmaxf(v.z, 0.f); v.w = fmaxf(v.w, 0.f);
            }
            *(float4*)(Cm + (size_t)m * N + n) = v;
        }
    }
}

// ---------------- step-0 sampling: argmax(epost[:,0] + gumbel[0]) ----------------
__global__ __launch_bounds__(256) void samp0_k(const float* __restrict__ epost, const float* __restrict__ gumbel,
                                               float* __restrict__ samples_out, int* __restrict__ sidx)
{
    int b = blockIdx.x;
    int tid = threadIdx.x;
    int l = tid >> 3, s = tid & 7;
    const float* lg = epost + ((size_t)b * TT + 0) * HH + l * 32;
    const float* gm = gumbel + (((size_t)0 * BB + b) * LL + l) * CC;
    float u[4];
    #pragma unroll
    for (int i = 0; i < 4; ++i) { int c = s * 4 + i; u[i] = lg[c] + gm[c]; }
    float best = u[0]; int bi = s * 4;
    #pragma unroll
    for (int i = 1; i < 4; ++i) { if (u[i] > best) { best = u[i]; bi = s * 4 + i; } }
    for (int m = 1; m < 8; m <<= 1) {
        float ov = __shfl_xor(best, m, 8);
        int   oi = __shfl_xor(bi, m, 8);
        if (ov > best || (ov == best && oi < bi)) { best = ov; bi = oi; }
    }
    float* so = samples_out + ((size_t)b * T1 + 0) * HH + l * 32;
    #pragma unroll
    for (int i = 0; i < 4; ++i) { int c = s * 4 + i; so[c] = (c == bi) ? 1.f : 0.f; }
    if (s == 0) sidx[((size_t)0 * BB + b) * LL + l] = bi;
}

// ---------------- lightweight device-scope barrier ----------------
// One counter per barrier instance (never reused within a dispatch); counters
// zeroed via hipMemsetAsync before launch. Leader: acq_rel arrive + acquire spin.
__device__ __forceinline__ void gbar(unsigned int* cnt, int bi)
{
    __syncthreads();   // compiler emits s_waitcnt vmcnt(0) lgkmcnt(0) before s_barrier
    if (threadIdx.x == 0) {
        __hip_atomic_fetch_add(&cnt[bi], 1u, __ATOMIC_ACQ_REL, __HIP_MEMORY_SCOPE_AGENT);
        while (__hip_atomic_load(&cnt[bi], __ATOMIC_ACQUIRE, __HIP_MEMORY_SCOPE_AGENT) < NWG)
            __builtin_amdgcn_s_sleep(2);
    }
    __syncthreads();
}

// ---------------- persistent scan kernel (custom barrier, no grid.sync) ----------------
// 256 blocks x 512 threads, 1 block/CU. Two barriers per step.
// Cross-block data within the dispatch: hseq[t][b][j] (one-shot addresses, written
// with agent-scope atomic stores -> MALL, read with plain vector loads) and sidx
// (same scheme). hso/plog/smo are read only by later dispatches -> plain stores.
__global__ __launch_bounds__(512) void scan_k(
    float* __restrict__ hseq, float* __restrict__ hso,
    const float* __restrict__ wihT, const float* __restrict__ whh,
    const float* __restrict__ bih, const float* __restrict__ bhh,
    int* __restrict__ sidx, const int* __restrict__ act,
    const float* __restrict__ postw, const float* __restrict__ epost,
    const float* __restrict__ gum, float* __restrict__ plog,
    float* __restrict__ smo, unsigned int* __restrict__ cnt)
{
    __shared__ __align__(16) char smraw[129664];
    // persistent whh stage: [2][12][516] floats = 49,536 B
    float (*wfull)[12][516] = (float(*)[12][516])smraw;
    char* U = smraw + 49536;
    // phase A views (80,128 B)
    float (*h_s)[64][132] = (float(*)[64][132])U;          // 67,584
    int   (*off_s)[33]    = (int(*)[33])(U + 67584);       //  8,448
    float (*ps)[4]        = (float(*)[4])(U + 76032);      //  4,096
    // phase B views (43,264 B)
    float (*hb_s)[8][132]  = (float(*)[8][132])U;          //  8,448
    float (*wb_s)[32][132] = (float(*)[32][132])(U + 8448);// 33,792
    float* psb             = (float*)(U + 42240);          //  1,024

    int tid = threadIdx.x;
    int kh = tid >> 8;              // K-half 0/1
    int r  = tid & 255;
    int bid = blockIdx.x;
    // phase A ids
    int sb = (bid & 7) * 32 + (bid >> 3);
    int j0 = sb * 4;
    int ab = r >> 2, q = r & 3, j = j0 + q;
    // phase B ids
    int l  = bid & 31;
    int bc = bid >> 5;
    int b0 = bc * 8;
    int b8 = r >> 5;
    int c  = r & 31;
    int n0 = l * 32;

    // stage whh once: rows rr=gate*4+qq -> whh[gate*1024 + j0 + qq][:]
    for (int i = tid; i < 3072; i += 512) {
        int k4 = i & 127;
        int rowi = i >> 7;          // 0..23
        int kh2 = (rowi >= 12) ? 1 : 0;
        int rr = rowi - kh2 * 12;
        int g = (rr >> 2) * 1024 + j0 + (rr & 3);
        *(float4*)&wfull[kh2][rr][k4 * 4] = ld4(whh + (size_t)g * HH + kh2 * 512 + k4 * 4);
    }
    __syncthreads();

    const int kbase = kh * 512;

    for (int t = 1; t <= 127; ++t) {
        // ================= phase A: h_t = GRU(h_{t-1}, [samp_{t-1}, a_{t-1}]) =========
        {
            const float* hprev = hseq + (size_t)(t - 1) * 65536;   // one-shot slice
            const int* sidx_prev = sidx + (size_t)(t - 1) * 2048;

            for (int i = tid; i < 64 * 33; i += 512) {
                int bb = i / 33, ll = i - bb * 33;
                off_s[bb][ll] = (ll < 32) ? (ll * 32 + sidx_prev[bb * 32 + ll])
                                          : (1024 + act[bb * TT + (t - 1)]);
            }
            __syncthreads();

            // gather partials (one-hot rows of wihT); n-gate gather (g2) kept
            // separate from h-dot (a2): n = tanh(inn + r*hn)
            float a0 = 0.f, a1 = 0.f, a2 = 0.f, g2 = 0.f;
            if (kh == 0) {
                #pragma unroll
                for (int i = 0; i < 17; ++i) {
                    int o = off_s[ab][i];
                    const float* wp = wihT + (size_t)o * G3 + j;
                    a0 += wp[0]; a1 += wp[1024]; g2 += wp[2048];
                }
            } else {
                #pragma unroll
                for (int i = 17; i < 33; ++i) {
                    int o = off_s[ab][i];
                    const float* wp = wihT + (size_t)o * G3 + j;
                    a0 += wp[0]; a1 += wp[1024]; g2 += wp[2048];
                }
            }

            // h dots over this K-half, register-prefetched h staging
            float4 hreg[8];
            auto loadH = [&](int kc) {
                #pragma unroll
                for (int m = 0; m < 8; ++m) {
                    int i = r + m * 256;
                    int row = i >> 5, c4 = i & 31;
                    hreg[m] = ld4(hprev + row * HH + kbase + kc * 128 + c4 * 4);
                }
            };
            loadH(0);
            for (int kc = 0; kc < 4; ++kc) {
                #pragma unroll
                for (int m = 0; m < 8; ++m) {
                    int i = r + m * 256;
                    int row = i >> 5, c4 = i & 31;
                    *(float4*)&h_s[kh][row][c4 * 4] = hreg[m];
                }
                __syncthreads();
                if (kc < 3) loadH(kc + 1);
                #pragma unroll 8
                for (int k4 = 0; k4 < 32; ++k4) {
                    float4 hv = *(const float4*)&h_s[kh][ab][k4 * 4];
                    float4 w0 = *(const float4*)&wfull[kh][q][kc * 128 + k4 * 4];
                    float4 w1 = *(const float4*)&wfull[kh][4 + q][kc * 128 + k4 * 4];
                    float4 w2 = *(const float4*)&wfull[kh][8 + q][kc * 128 + k4 * 4];
                    a0 += hv.x * w0.x + hv.y * w0.y + hv.z * w0.z + hv.w * w0.w;
                    a1 += hv.x * w1.x + hv.y * w1.y + hv.z * w1.z + hv.w * w1.w;
                    a2 += hv.x * w2.x + hv.y * w2.y + hv.z * w2.z + hv.w * w2.w;
                }
                __syncthreads();
            }
            if (kh == 1) { ps[r][0] = a0; ps[r][1] = a1; ps[r][2] = a2; ps[r][3] = g2; }
            __syncthreads();
            if (kh == 0) {
                float s0 = a0 + ps[r][0];
                float s1 = a1 + ps[r][1];
                float hn = a2 + ps[r][2] + bhh[2048 + j];
                float inn = g2 + ps[r][3] + bih[2048 + j];
                float rr = 1.f / (1.f + expf(-(s0 + bih[j] + bhh[j])));
                float zz = 1.f / (1.f + expf(-(s1 + bih[1024 + j] + bhh[1024 + j])));
                float nn = tanhf(inn + rr * hn);
                float hp = hprev[ab * HH + j];
                float hv = (1.f - zz) * nn + zz * hp;
                // cross-block (in-kernel) copy: write-through to MALL, one-shot address
                __hip_atomic_store(&hseq[(size_t)t * 65536 + ab * HH + j], hv,
                                   __ATOMIC_RELAXED, __HIP_MEMORY_SCOPE_AGENT);
                // post-scan consumer only: plain store
                hso[((size_t)ab * T1 + (t - 1)) * HH + j] = hv;
            }
        }
        gbar(cnt, (t - 1) * 2);

        // ================= phase B: logits_t = h_t @ postw_top + epost[:,t]; sample ==
        {
            const float* hcur = hseq + (size_t)t * 65536;   // one-shot slice, plain reads
            float acc = 0.f;
            for (int kc = 0; kc < 4; ++kc) {
                int kb = kbase + kc * 128;
                {
                    int row = r >> 5, c4 = r & 31;
                    *(float4*)&hb_s[kh][row][c4 * 4] = ld4(hcur + (b0 + row) * HH + kb + c4 * 4);
                }
                for (int i = r; i < 4096; i += 256) {
                    int k = i >> 5, cc = i & 31;
                    wb_s[kh][cc][k] = postw[(size_t)(kb + k) * HH + n0 + cc];
                }
                __syncthreads();
                #pragma unroll 8
                for (int k4 = 0; k4 < 32; ++k4) {
                    float4 hv = *(const float4*)&hb_s[kh][b8][k4 * 4];
                    float4 wv = *(const float4*)&wb_s[kh][c][k4 * 4];
                    acc += hv.x * wv.x + hv.y * wv.y + hv.z * wv.z + hv.w * wv.w;
                }
                __syncthreads();
            }
            if (kh == 1) psb[r] = acc;
            __syncthreads();
            if (kh == 0) {
                int b = b0 + b8;
                int n = n0 + c;
                float lg = acc + psb[r] + epost[((size_t)b * TT + t) * HH + n];
                plog[((size_t)(t - 1) * BB + b) * HH + n] = lg;
                if (t <= 126) {
                    float u = lg + gum[(((size_t)t * BB + b) * LL + l) * CC + c];
                    float best = u; int bi = c;
                    for (int m = 1; m < 32; m <<= 1) {
                        float ov = __shfl_xor(best, m, 32);
                        int   oi = __shfl_xor(bi, m, 32);
                        if (ov > best || (ov == best && oi < bi)) { best = ov; bi = oi; }
                    }
                    smo[((size_t)b * T1 + t) * HH + n] = (c == bi) ? 1.f : 0.f;
                    if (c == 0)
                        __hip_atomic_store(&sidx[((size_t)t * BB + b) * LL + l], bi,
                                           __ATOMIC_RELAXED, __HIP_MEMORY_SCOPE_AGENT);
                }
            }
        }
        if (t < 127) gbar(cnt, (t - 1) * 2 + 1);   // last step: dispatch-end release suffices
    }
}

// ---------------- KL reduction ----------------
__global__ __launch_bounds__(256) void kl_k(const float* __restrict__ prior,
    const float* __restrict__ plog, float* __restrict__ out)
{
    int rrow = blockIdx.x;              // b*127 + i
    int b = rrow / T1, i = rrow - b * T1;
    int tid = threadIdx.x;
    int l = tid >> 3, s = tid & 7;
    const float* pp = prior + (size_t)rrow * HH + l * 32;
    const float* qq = plog + ((size_t)i * BB + b) * HH + l * 32;
    float pv[4], qv[4];
    #pragma unroll
    for (int e = 0; e < 4; ++e) { int c = s * 4 + e; pv[e] = pp[c]; qv[e] = qq[c]; }
    float mp = fmaxf(fmaxf(pv[0], pv[1]), fmaxf(pv[2], pv[3]));
    float mq = fmaxf(fmaxf(qv[0], qv[1]), fmaxf(qv[2], qv[3]));
    for (int m = 1; m < 8; m <<= 1) {
        mp = fmaxf(mp, __shfl_xor(mp, m, 8));
        mq = fmaxf(mq, __shfl_xor(mq, m, 8));
    }
    float sp = 0.f, sq = 0.f;
    #pragma unroll
    for (int e = 0; e < 4; ++e) { sp += expf(pv[e] - mp); sq += expf(qv[e] - mq); }
    for (int m = 1; m < 8; m <<= 1) { sp += __shfl_xor(sp, m, 8); sq += __shfl_xor(sq, m, 8); }
    float lsp = mp + logf(sp), lsq = mq + logf(sq);
    float kf = 0.f, kr = 0.f;
    #pragma unroll
    for (int e = 0; e < 4; ++e) {
        float lp = pv[e] - lsp, lq = qv[e] - lsq;
        float eq = expf(lq), ep = expf(lp);
        kf += eq * (lq - lp); kr += ep * (lp - lq);
    }
    for (int m = 1; m < 8; m <<= 1) { kf += __shfl_xor(kf, m, 8); kr += __shfl_xor(kr, m, 8); }
    __shared__ float kfs[32], krs[32];
    if (s == 0) { kfs[l] = kf; krs[l] = kr; }
    __syncthreads();
    if (tid == 0) {
        float f = 0.f, r = 0.f;
        for (int l2 = 0; l2 < 32; ++l2) { f += kfs[l2]; r += krs[l2]; }
        float val = fmaxf(0.8f * f + 0.2f * r, 1.0f);
        atomicAdd(out, val * (1.0f / 8128.0f));
    }
}

// ---------------- gather-sum of dec_w1 bottom rows per (b,i) ----------------
__global__ __launch_bounds__(256) void gsum_k(const float* __restrict__ dw1bot,
    const int* __restrict__ sidx, float* __restrict__ gsum)
{
    int rrow = blockIdx.x;              // b*127 + i
    int b = rrow / T1, i = rrow - b * T1;
    __shared__ int offs[32];
    int tid = threadIdx.x;
    if (tid < 32) offs[tid] = tid * 32 + sidx[((size_t)i * BB + b) * LL + tid];
    __syncthreads();
    int n = tid * 4;
    float4 acc = make_float4(0.f, 0.f, 0.f, 0.f);
    #pragma unroll 4
    for (int l = 0; l < 32; ++l) {
        float4 v = ld4(dw1bot + (size_t)offs[l] * HH + n);
        acc.x += v.x; acc.y += v.y; acc.z += v.z; acc.w += v.w;
    }
    *(float4*)(gsum + (size_t)rrow * HH + n) = acc;
}

// ---------------- reward head ----------------
__global__ __launch_bounds__(256) void rew_k(const float* __restrict__ hs, const float* __restrict__ reww,
    const float* __restrict__ rewb, const int* __restrict__ sidx, float* __restrict__ pred)
{
    int rrow = blockIdx.x * 4 + (threadIdx.x >> 6);
    int lane = threadIdx.x & 63;
    int b = rrow / T1, i = rrow - b * T1;
    const float* hp = hs + (size_t)rrow * HH;
    float acc = 0.f;
    for (int k = lane; k < HH; k += 64) acc += hp[k] * reww[k];
    for (int m = 1; m < 64; m <<= 1) acc += __shfl_xor(acc, m, 64);
    if (lane == 0) {
        float g = 0.f;
        const int* sp = sidx + ((size_t)i * BB + b) * LL;
        for (int l = 0; l < 32; ++l) g += reww[1024 + l * 32 + sp[l]];
        pred[rrow] = acc + g + rewb[0];
    }
}

extern "C" void kernel_launch(void* const* d_in, const int* in_sizes, int n_in,
                              void* d_out, int out_size, void* d_ws, size_t ws_size,
                              hipStream_t stream) {
    const float* obs   = (const float*)d_in[0];
    const float* gum   = (const float*)d_in[1];
    const float* ew1   = (const float*)d_in[2];
    const float* eb1   = (const float*)d_in[3];
    const float* ew2   = (const float*)d_in[4];
    const float* eb2   = (const float*)d_in[5];
    const float* wih   = (const float*)d_in[6];
    const float* whh   = (const float*)d_in[7];
    const float* bih   = (const float*)d_in[8];
    const float* bhh   = (const float*)d_in[9];
    const float* priw  = (const float*)d_in[10];
    const float* prib  = (const float*)d_in[11];
    const float* postw = (const float*)d_in[12];
    const float* postb = (const float*)d_in[13];
    const float* dw1   = (const float*)d_in[14];
    const float* db1   = (const float*)d_in[15];
    const float* dw2   = (const float*)d_in[16];
    const float* db2   = (const float*)d_in[17];
    const float* reww  = (const float*)d_in[18];
    const float* rewb  = (const float*)d_in[19];
    const int*   act   = (const int*)d_in[20];
    (void)in_sizes; (void)n_in; (void)out_size; (void)ws_size;

    float* ws = (float*)d_ws;
    float* wihT = ws;                       // 1042*3072 = 3,201,024
    float* bufA = wihT + 3201024;           // 8192*1024 : e1 -> epost -> prior_logits
    float* bufB = bufA + 8388608;           // 8192*1024 : e -> hseq[128][64][1024] -> dec_tmp
    float* plog = bufB + 8388608;           // 127*64*1024 : post_logits -> gsum
    int*   sidx = (int*)(plog + 8323072);   // 127*64*32 ints = 260,096
    unsigned int* cnt = (unsigned int*)(sidx + 260096);  // 253 barrier counters

    float* out = (float*)d_out;
    float* recon = out;                     // 8128*512
    float* pred  = out + 4161536;           // 8128
    float* klo   = pred + 8128;             // 1
    float* hso   = klo + 1;                 // 8128*1024 (NOT 16B-aligned: scalar/AAL=0 paths only)
    float* smo   = hso + 8323072;           // 8128*1024

    hipMemsetAsync(klo, 0, sizeof(float), stream);
    hipMemsetAsync(cnt, 0, 256 * sizeof(unsigned int), stream);

    tr_k<<<dim3(96, 33), dim3(32, 8), 0, stream>>>(wih, wihT);
    // encoder (e written into bufB's tail region is fine: hseq[0] zeroed after)
    gemm_k<1,0,1><<<dim3(8, 64), 256, 0, stream>>>(obs,  ew1, bufA, 8192, 1024, 512,  eb1, nullptr);
    gemm_k<1,0,1><<<dim3(8, 64), 256, 0, stream>>>(bufA, ew2, bufB, 8192, 1024, 1024, eb2, nullptr);
    // epost = e @ post_w[1024:] + post_b  (hoisted e-half of posterior logits)
    gemm_k<0,0,1><<<dim3(8, 64), 256, 0, stream>>>(bufB, postw + 1024 * 1024, bufA, 8192, 1024, 1024, postb, nullptr);
    // step-0 sample
    samp0_k<<<64, 256, 0, stream>>>(bufA, gum, smo, sidx);

    // hseq[0] = h0 = zeros (bufB's e-content no longer needed)
    hipMemsetAsync(bufB, 0, 65536 * sizeof(float), stream);

    // persistent scan (127 steps, 2 lightweight barriers per step; coop launch for residency)
    {
        float* hseq_p = bufB; float* hso_p = hso;
        const float* wihT_p = wihT; const float* whh_p = whh;
        const float* bih_p = bih; const float* bhh_p = bhh;
        int* sidx_p = sidx; const int* act_p = act;
        const float* postw_p = postw; const float* epost_p = bufA;
        const float* gum_p = gum; float* plog_p = plog; float* smo_p = smo;
        unsigned int* cnt_p = cnt;
        void* args[] = { &hseq_p, &hso_p, &wihT_p, &whh_p, &bih_p, &bhh_p,
                         &sidx_p, &act_p, &postw_p, &epost_p, &gum_p, &plog_p, &smo_p, &cnt_p };
        hipLaunchCooperativeKernel((const void*)scan_k, dim3(256), dim3(512), args, 0, stream);
    }

    // prior logits (A=hso is not 16B-aligned -> AAL=0)
    gemm_k<0,0,0><<<dim3(8, 64), 256, 0, stream>>>(hso, priw, bufA, 8128, 1024, 1024, prib, nullptr);
    // KL
    kl_k<<<8128, 256, 0, stream>>>(bufA, plog, klo);
    // decoder: gather-sum then 2 GEMMs (bufB reused as dec_tmp; hseq dead)
    gsum_k<<<8128, 256, 0, stream>>>(dw1 + 1024 * 1024, sidx, plog);
    gemm_k<1,1,0><<<dim3(8, 64), 256, 0, stream>>>(hso, dw1, bufB, 8128, 1024, 1024, db1, plog);
    gemm_k<0,0,1><<<dim3(4, 64), 256, 0, stream>>>(bufB, dw2, recon, 8128, 512, 1024, db2, nullptr);
    // reward
    rew_k<<<2032, 256, 0, stream>>>(hso, reww, rewb, sidx, pred);
}

// Round 5
// 6421.975 us; speedup vs baseline: 3.7996x; 1.6900x over previous
//
#include <hip/hip_runtime.h>
#include <hip/hip_bf16.h>
#include <math.h>

// Problem dims
#define BB 64
#define TT 128
#define T1 127
#define OBS 512
#define HH 1024
#define LL 32
#define CC 32
#define AA 18
#define KIN 1042   // LC + A
#define G3 3072    // 3*H
#define NWG 256

__device__ __forceinline__ float4 ld4(const float* p) { return *(const float4*)p; }

// ---------------- transpose wih (3072 x 1042) -> wihT (1042 x 3072) ----------------
__global__ __launch_bounds__(256) void tr_k(const float* __restrict__ wih, float* __restrict__ wihT)
{
    __shared__ float tile[32][33];
    int g0 = blockIdx.x * 32;   // 96
    int k0 = blockIdx.y * 32;   // 33 (covers 1056, guard 1042)
    int tx = threadIdx.x, ty = threadIdx.y; // 32 x 8
    #pragma unroll
    for (int r = 0; r < 32; r += 8) {
        int g = g0 + ty + r, k = k0 + tx;
        tile[ty + r][tx] = (k < KIN) ? wih[(size_t)g * KIN + k] : 0.f;
    }
    __syncthreads();
    #pragma unroll
    for (int r = 0; r < 32; r += 8) {
        int k = k0 + ty + r, g = g0 + tx;
        if (k < KIN) wihT[(size_t)k * G3 + g] = tile[tx][ty + r];
    }
}

// ---------------- transpose postw top half (1024 x 1024) -> postwT (n-major) --------
__global__ __launch_bounds__(256) void tr2_k(const float* __restrict__ src, float* __restrict__ dst)
{
    __shared__ float tile[32][33];
    int r0 = blockIdx.x * 32;   // src row (k)
    int c0 = blockIdx.y * 32;   // src col (n)
    int tx = threadIdx.x, ty = threadIdx.y;
    #pragma unroll
    for (int rr = 0; rr < 32; rr += 8)
        tile[ty + rr][tx] = src[(size_t)(r0 + ty + rr) * HH + c0 + tx];
    __syncthreads();
    #pragma unroll
    for (int rr = 0; rr < 32; rr += 8)
        dst[(size_t)(c0 + ty + rr) * HH + r0 + tx] = tile[tx][ty + rr];
}

// ---------------- fp32 GEMM: C = A(MxK) @ B(KxN) + bias (+extra) (relu) --------------
// tile 128x128, 256 threads, 8x8 micro, ktile 16, register-prefetch double buffer
template<int RELU, int HAS_EXTRA, int AAL>
__global__ __launch_bounds__(256) void gemm_k(const float* __restrict__ A, const float* __restrict__ Bm,
    float* __restrict__ Cm, int M, int N, int K,
    const float* __restrict__ bias, const float* __restrict__ extra)
{
    __shared__ float As[16][132];
    __shared__ float Bs[16][132];
    int tid = threadIdx.x;
    int tx = tid & 15, ty = tid >> 4;
    int m0 = blockIdx.y * 128, n0 = blockIdx.x * 128;
    float acc[8][8];
    #pragma unroll
    for (int i = 0; i < 8; ++i)
        #pragma unroll
        for (int j = 0; j < 8; ++j) acc[i][j] = 0.f;

    int arow = tid >> 1;
    int ak0  = (tid & 1) * 8;   // k offset 0 or 8
    int am   = m0 + arow;

    float  ar[8];
    float4 br[2];

    auto loadA = [&](int kt) {
        if (am < M) {
            const float* ap = A + (size_t)am * K + kt + ak0;
            if (AAL) {
                float4 v0 = ld4(ap), v1 = ld4(ap + 4);
                ar[0] = v0.x; ar[1] = v0.y; ar[2] = v0.z; ar[3] = v0.w;
                ar[4] = v1.x; ar[5] = v1.y; ar[6] = v1.z; ar[7] = v1.w;
            } else {
                #pragma unroll
                for (int e = 0; e < 8; ++e) ar[e] = ap[e];
            }
        } else {
            #pragma unroll
            for (int e = 0; e < 8; ++e) ar[e] = 0.f;
        }
    };
    auto loadB = [&](int kt) {
        #pragma unroll
        for (int i2 = 0; i2 < 2; ++i2) {
            int idx = tid * 2 + i2;         // 0..511
            int kk = idx >> 5, c4 = idx & 31;
            br[i2] = ld4(Bm + (size_t)(kt + kk) * N + n0 + c4 * 4);
        }
    };

    loadA(0); loadB(0);

    for (int kt = 0; kt < K; kt += 16) {
        // write prefetched regs -> LDS
        #pragma unroll
        for (int e = 0; e < 8; ++e) As[ak0 + e][arow] = ar[e];
        #pragma unroll
        for (int i2 = 0; i2 < 2; ++i2) {
            int idx = tid * 2 + i2;
            int kk = idx >> 5, c4 = idx & 31;
            *(float4*)&Bs[kk][c4 * 4] = br[i2];
        }
        __syncthreads();
        if (kt + 16 < K) { loadA(kt + 16); loadB(kt + 16); }
        #pragma unroll
        for (int k = 0; k < 16; ++k) {
            float av[8], bv[8];
            *(float4*)&av[0] = *(const float4*)&As[k][ty * 8];
            *(float4*)&av[4] = *(const float4*)&As[k][ty * 8 + 4];
            *(float4*)&bv[0] = *(const float4*)&Bs[k][tx * 8];
            *(float4*)&bv[4] = *(const float4*)&Bs[k][tx * 8 + 4];
            #pragma unroll
            for (int i = 0; i < 8; ++i)
                #pragma unroll
                for (int j = 0; j < 8; ++j)
                    acc[i][j] = fmaf(av[i], bv[j], acc[i][j]);
        }
        __syncthreads();
    }
    #pragma unroll
    for (int i = 0; i < 8; ++i) {
        int m = m0 + ty * 8 + i;
        if (m >= M) break;
        #pragma unroll
        for (int jh = 0; jh < 2; ++jh) {
            int n = n0 + tx * 8 + jh * 4;
            float4 v;
            v.x = acc[i][jh * 4 + 0] + bias[n + 0];
            v.y = acc[i][jh * 4 + 1] + bias[n + 1];
            v.z = acc[i][jh * 4 + 2] + bias[n + 2];
            v.w = acc[i][jh * 4 + 3] + bias[n + 3];
            if (HAS_EXTRA) {
                float4 e = ld4(extra + (size_t)m * N + n);
                v.x += e.x; v.y += e.y; v.z += e.z; v.w += e.w;
            }
            if (RELU) {
                v.x = fmaxf(v.x, 0.f); v.y = fmaxf(v.y, 0.f);
                v.z = fmaxf(v.z, 0.f); v.w = fmaxf(v.w, 0.f);
            }
            *(float4*)(Cm + (size_t)m * N + n) = v;
        }
    }
}

// ---------------- step-0 sampling: argmax(epost[:,0] + gumbel[0]) ----------------
__global__ __launch_bounds__(256) void samp0_k(const float* __restrict__ epost, const float* __restrict__ gumbel,
                                               float* __restrict__ samples_out, int* __restrict__ sidx)
{
    int b = blockIdx.x;
    int tid = threadIdx.x;
    int l = tid >> 3, s = tid & 7;
    const float* lg = epost + ((size_t)b * TT + 0) * HH + l * 32;
    const float* gm = gumbel + (((size_t)0 * BB + b) * LL + l) * CC;
    float u[4];
    #pragma unroll
    for (int i = 0; i < 4; ++i) { int c = s * 4 + i; u[i] = lg[c] + gm[c]; }
    float best = u[0]; int bi = s * 4;
    #pragma unroll
    for (int i = 1; i < 4; ++i) { if (u[i] > best) { best = u[i]; bi = s * 4 + i; } }
    for (int m = 1; m < 8; m <<= 1) {
        float ov = __shfl_xor(best, m, 8);
        int   oi = __shfl_xor(bi, m, 8);
        if (ov > best || (ov == best && oi < bi)) { best = ov; bi = oi; }
    }
    float* so = samples_out + ((size_t)b * T1 + 0) * HH + l * 32;
    #pragma unroll
    for (int i = 0; i < 4; ++i) { int c = s * 4 + i; so[c] = (c == bi) ? 1.f : 0.f; }
    if (s == 0) sidx[((size_t)0 * BB + b) * LL + l] = bi;
}

// ---------------- flag-array device barrier: ZERO cache-maintenance ops ------------
// One flag per (barrier instance, block); flags zeroed before launch. Arrive = one
// relaxed agent-scope store (sc1 write-through). Wait = wave 0 polls all 256 flags
// with relaxed agent-scope loads (served at MALL; no buffer_inv). Insurance
// escalation (release+acquire) only if stuck ~2048 polls — free on the fast path.
__device__ __forceinline__ void gbar(unsigned int* __restrict__ flags, int bi, int bid)
{
    __syncthreads();   // per-wave s_waitcnt vmcnt(0): all prior stores completed @MALL
    unsigned int* f = flags + (size_t)bi * NWG;
    int tid = threadIdx.x;
    if (tid < 64) {
        if (tid == 0)
            __hip_atomic_store(&f[bid], 1u, __ATOMIC_RELAXED, __HIP_MEMORY_SCOPE_AGENT);
        int it = 0;
        for (;;) {
            unsigned int v0 = __hip_atomic_load(&f[tid],       __ATOMIC_RELAXED, __HIP_MEMORY_SCOPE_AGENT);
            unsigned int v1 = __hip_atomic_load(&f[64 + tid],  __ATOMIC_RELAXED, __HIP_MEMORY_SCOPE_AGENT);
            unsigned int v2 = __hip_atomic_load(&f[128 + tid], __ATOMIC_RELAXED, __HIP_MEMORY_SCOPE_AGENT);
            unsigned int v3 = __hip_atomic_load(&f[192 + tid], __ATOMIC_RELAXED, __HIP_MEMORY_SCOPE_AGENT);
            if (__all((v0 & v1 & v2 & v3) != 0)) break;
            __builtin_amdgcn_s_sleep(4);
            if (((++it) & 2047) == 2047 && tid == 0) {
                __hip_atomic_store(&f[bid], 1u, __ATOMIC_RELEASE, __HIP_MEMORY_SCOPE_AGENT);
                (void)__hip_atomic_load(&f[bid], __ATOMIC_ACQUIRE, __HIP_MEMORY_SCOPE_AGENT);
            }
        }
    }
    __syncthreads();
}

// ---------------- persistent scan kernel ----------------
// 256 blocks x 512 threads, 1 block/CU. Two flag-barriers per step.
// Cross-block in-kernel data (hseq, sidx): one-shot addresses, agent-scope relaxed
// atomic stores (write-through to MALL), plain clean-fill reads after the barrier.
__global__ __launch_bounds__(512) void scan_k(
    float* __restrict__ hseq, float* __restrict__ hso,
    const float* __restrict__ wihT, const float* __restrict__ whh,
    const float* __restrict__ bih, const float* __restrict__ bhh,
    int* __restrict__ sidx, const int* __restrict__ act,
    const float* __restrict__ postwT, const float* __restrict__ epost,
    const float* __restrict__ gum, float* __restrict__ plog,
    float* __restrict__ smo, unsigned int* __restrict__ flags)
{
    __shared__ __align__(16) char smraw[129664];
    // persistent whh stage: [2][12][516] floats = 49,536 B
    float (*wfull)[12][516] = (float(*)[12][516])smraw;
    char* U = smraw + 49536;
    // phase A views (80,128 B)
    float (*h_s)[64][132] = (float(*)[64][132])U;          // 67,584
    int   (*off_s)[33]    = (int(*)[33])(U + 67584);       //  8,448
    float (*ps)[4]        = (float(*)[4])(U + 76032);      //  4,096
    // phase B views (43,264 B)
    float (*hb_s)[8][132]  = (float(*)[8][132])U;          //  8,448
    float (*wb_s)[32][132] = (float(*)[32][132])(U + 8448);// 33,792
    float* psb             = (float*)(U + 42240);          //  1,024

    int tid = threadIdx.x;
    int kh = tid >> 8;              // K-half 0/1
    int r  = tid & 255;
    int bid = blockIdx.x;
    // phase A ids
    int sb = (bid & 7) * 32 + (bid >> 3);
    int j0 = sb * 4;
    int ab = r >> 2, q = r & 3, j = j0 + q;
    // phase B ids
    int l  = bid & 31;
    int bc = bid >> 5;
    int b0 = bc * 8;
    int b8 = r >> 5;
    int c  = r & 31;
    int n0 = l * 32;

    // stage whh once: rows rr=gate*4+qq -> whh[gate*1024 + j0 + qq][:]
    for (int i = tid; i < 3072; i += 512) {
        int k4 = i & 127;
        int rowi = i >> 7;          // 0..23
        int kh2 = (rowi >= 12) ? 1 : 0;
        int rr = rowi - kh2 * 12;
        int g = (rr >> 2) * 1024 + j0 + (rr & 3);
        *(float4*)&wfull[kh2][rr][k4 * 4] = ld4(whh + (size_t)g * HH + kh2 * 512 + k4 * 4);
    }
    __syncthreads();

    const int kbase = kh * 512;

    for (int t = 1; t <= 127; ++t) {
        // ================= phase A: h_t = GRU(h_{t-1}, [samp_{t-1}, a_{t-1}]) =========
        {
            const float* hprev = hseq + (size_t)(t - 1) * 65536;   // one-shot slice
            const int* sidx_prev = sidx + (size_t)(t - 1) * 2048;

            for (int i = tid; i < 64 * 33; i += 512) {
                int bb = i / 33, ll = i - bb * 33;
                off_s[bb][ll] = (ll < 32) ? (ll * 32 + sidx_prev[bb * 32 + ll])
                                          : (1024 + act[bb * TT + (t - 1)]);
            }
            __syncthreads();

            // gather partials (one-hot rows of wihT); n-gate gather (g2) kept
            // separate from h-dot (a2): n = tanh(inn + r*hn)
            float a0 = 0.f, a1 = 0.f, a2 = 0.f, g2 = 0.f;
            if (kh == 0) {
                #pragma unroll
                for (int i = 0; i < 17; ++i) {
                    int o = off_s[ab][i];
                    const float* wp = wihT + (size_t)o * G3 + j;
                    a0 += wp[0]; a1 += wp[1024]; g2 += wp[2048];
                }
            } else {
                #pragma unroll
                for (int i = 17; i < 33; ++i) {
                    int o = off_s[ab][i];
                    const float* wp = wihT + (size_t)o * G3 + j;
                    a0 += wp[0]; a1 += wp[1024]; g2 += wp[2048];
                }
            }

            // h dots over this K-half, register-prefetched h staging
            float4 hreg[8];
            auto loadH = [&](int kc) {
                #pragma unroll
                for (int m = 0; m < 8; ++m) {
                    int i = r + m * 256;
                    int row = i >> 5, c4 = i & 31;
                    hreg[m] = ld4(hprev + row * HH + kbase + kc * 128 + c4 * 4);
                }
            };
            loadH(0);
            for (int kc = 0; kc < 4; ++kc) {
                #pragma unroll
                for (int m = 0; m < 8; ++m) {
                    int i = r + m * 256;
                    int row = i >> 5, c4 = i & 31;
                    *(float4*)&h_s[kh][row][c4 * 4] = hreg[m];
                }
                __syncthreads();
                if (kc < 3) loadH(kc + 1);
                #pragma unroll 8
                for (int k4 = 0; k4 < 32; ++k4) {
                    float4 hv = *(const float4*)&h_s[kh][ab][k4 * 4];
                    float4 w0 = *(const float4*)&wfull[kh][q][kc * 128 + k4 * 4];
                    float4 w1 = *(const float4*)&wfull[kh][4 + q][kc * 128 + k4 * 4];
                    float4 w2 = *(const float4*)&wfull[kh][8 + q][kc * 128 + k4 * 4];
                    a0 += hv.x * w0.x + hv.y * w0.y + hv.z * w0.z + hv.w * w0.w;
                    a1 += hv.x * w1.x + hv.y * w1.y + hv.z * w1.z + hv.w * w1.w;
                    a2 += hv.x * w2.x + hv.y * w2.y + hv.z * w2.z + hv.w * w2.w;
                }
                __syncthreads();
            }
            if (kh == 1) { ps[r][0] = a0; ps[r][1] = a1; ps[r][2] = a2; ps[r][3] = g2; }
            __syncthreads();
            if (kh == 0) {
                float s0 = a0 + ps[r][0];
                float s1 = a1 + ps[r][1];
                float hn = a2 + ps[r][2] + bhh[2048 + j];
                float inn = g2 + ps[r][3] + bih[2048 + j];
                float rr = 1.f / (1.f + expf(-(s0 + bih[j] + bhh[j])));
                float zz = 1.f / (1.f + expf(-(s1 + bih[1024 + j] + bhh[1024 + j])));
                float nn = tanhf(inn + rr * hn);
                float hp = hprev[ab * HH + j];
                float hv = (1.f - zz) * nn + zz * hp;
                // cross-block (in-kernel) value: write-through to MALL, one-shot address
                __hip_atomic_store(&hseq[(size_t)t * 65536 + ab * HH + j], hv,
                                   __ATOMIC_RELAXED, __HIP_MEMORY_SCOPE_AGENT);
                // post-scan consumer only: plain store
                hso[((size_t)ab * T1 + (t - 1)) * HH + j] = hv;
            }
        }
        gbar(flags, (t - 1) * 2, bid);

        // ================= phase B: logits_t = h_t @ postw_top + epost[:,t]; sample ==
        {
            const float* hcur = hseq + (size_t)t * 65536;   // one-shot slice, plain reads
            float acc = 0.f;
            for (int kc = 0; kc < 4; ++kc) {
                int kb = kbase + kc * 128;
                {
                    int row = r >> 5, c4 = r & 31;
                    *(float4*)&hb_s[kh][row][c4 * 4] = ld4(hcur + (b0 + row) * HH + kb + c4 * 4);
                }
                #pragma unroll
                for (int ii = 0; ii < 4; ++ii) {
                    int slot = r + ii * 256;            // 0..1023
                    int cc = slot >> 5, f4 = slot & 31;
                    *(float4*)&wb_s[kh][cc][f4 * 4] = ld4(postwT + (size_t)(n0 + cc) * HH + kb + f4 * 4);
                }
                __syncthreads();
                #pragma unroll 8
                for (int k4 = 0; k4 < 32; ++k4) {
                    float4 hv = *(const float4*)&hb_s[kh][b8][k4 * 4];
                    float4 wv = *(const float4*)&wb_s[kh][c][k4 * 4];
                    acc += hv.x * wv.x + hv.y * wv.y + hv.z * wv.z + hv.w * wv.w;
                }
                __syncthreads();
            }
            if (kh == 1) psb[r] = acc;
            __syncthreads();
            if (kh == 0) {
                int b = b0 + b8;
                int n = n0 + c;
                float lg = acc + psb[r] + epost[((size_t)b * TT + t) * HH + n];
                plog[((size_t)(t - 1) * BB + b) * HH + n] = lg;
                if (t <= 126) {
                    float u = lg + gum[(((size_t)t * BB + b) * LL + l) * CC + c];
                    float best = u; int bi = c;
                    for (int m = 1; m < 32; m <<= 1) {
                        float ov = __shfl_xor(best, m, 32);
                        int   oi = __shfl_xor(bi, m, 32);
                        if (ov > best || (ov == best && oi < bi)) { best = ov; bi = oi; }
                    }
                    smo[((size_t)b * T1 + t) * HH + n] = (c == bi) ? 1.f : 0.f;
                    if (c == 0)
                        __hip_atomic_store(&sidx[((size_t)t * BB + b) * LL + l], bi,
                                           __ATOMIC_RELAXED, __HIP_MEMORY_SCOPE_AGENT);
                }
            }
        }
        if (t < 127) gbar(flags, (t - 1) * 2 + 1, bid);   // last step: dispatch-end release suffices
    }
}

// ---------------- KL reduction ----------------
__global__ __launch_bounds__(256) void kl_k(const float* __restrict__ prior,
    const float* __restrict__ plog, float* __restrict__ out)
{
    int rrow = blockIdx.x;              // b*127 + i
    int b = rrow / T1, i = rrow - b * T1;
    int tid = threadIdx.x;
    int l = tid >> 3, s = tid & 7;
    const float* pp = prior + (size_t)rrow * HH + l * 32;
    const float* qq = plog + ((size_t)i * BB + b) * HH + l * 32;
    float pv[4], qv[4];
    #pragma unroll
    for (int e = 0; e < 4; ++e) { int c = s * 4 + e; pv[e] = pp[c]; qv[e] = qq[c]; }
    float mp = fmaxf(fmaxf(pv[0], pv[1]), fmaxf(pv[2], pv[3]));
    float mq = fmaxf(fmaxf(qv[0], qv[1]), fmaxf(qv[2], qv[3]));
    for (int m = 1; m < 8; m <<= 1) {
        mp = fmaxf(mp, __shfl_xor(mp, m, 8));
        mq = fmaxf(mq, __shfl_xor(mq, m, 8));
    }
    float sp = 0.f, sq = 0.f;
    #pragma unroll
    for (int e = 0; e < 4; ++e) { sp += expf(pv[e] - mp); sq += expf(qv[e] - mq); }
    for (int m = 1; m < 8; m <<= 1) { sp += __shfl_xor(sp, m, 8); sq += __shfl_xor(sq, m, 8); }
    float lsp = mp + logf(sp), lsq = mq + logf(sq);
    float kf = 0.f, kr = 0.f;
    #pragma unroll
    for (int e = 0; e < 4; ++e) {
        float lp = pv[e] - lsp, lq = qv[e] - lsq;
        float eq = expf(lq), ep = expf(lp);
        kf += eq * (lq - lp); kr += ep * (lp - lq);
    }
    for (int m = 1; m < 8; m <<= 1) { kf += __shfl_xor(kf, m, 8); kr += __shfl_xor(kr, m, 8); }
    __shared__ float kfs[32], krs[32];
    if (s == 0) { kfs[l] = kf; krs[l] = kr; }
    __syncthreads();
    if (tid == 0) {
        float f = 0.f, r = 0.f;
        for (int l2 = 0; l2 < 32; ++l2) { f += kfs[l2]; r += krs[l2]; }
        float val = fmaxf(0.8f * f + 0.2f * r, 1.0f);
        atomicAdd(out, val * (1.0f / 8128.0f));
    }
}

// ---------------- gather-sum of dec_w1 bottom rows per (b,i) ----------------
__global__ __launch_bounds__(256) void gsum_k(const float* __restrict__ dw1bot,
    const int* __restrict__ sidx, float* __restrict__ gsum)
{
    int rrow = blockIdx.x;              // b*127 + i
    int b = rrow / T1, i = rrow - b * T1;
    __shared__ int offs[32];
    int tid = threadIdx.x;
    if (tid < 32) offs[tid] = tid * 32 + sidx[((size_t)i * BB + b) * LL + tid];
    __syncthreads();
    int n = tid * 4;
    float4 acc = make_float4(0.f, 0.f, 0.f, 0.f);
    #pragma unroll 4
    for (int l = 0; l < 32; ++l) {
        float4 v = ld4(dw1bot + (size_t)offs[l] * HH + n);
        acc.x += v.x; acc.y += v.y; acc.z += v.z; acc.w += v.w;
    }
    *(float4*)(gsum + (size_t)rrow * HH + n) = acc;
}

// ---------------- reward head ----------------
__global__ __launch_bounds__(256) void rew_k(const float* __restrict__ hs, const float* __restrict__ reww,
    const float* __restrict__ rewb, const int* __restrict__ sidx, float* __restrict__ pred)
{
    int rrow = blockIdx.x * 4 + (threadIdx.x >> 6);
    int lane = threadIdx.x & 63;
    int b = rrow / T1, i = rrow - b * T1;
    const float* hp = hs + (size_t)rrow * HH;
    float acc = 0.f;
    for (int k = lane; k < HH; k += 64) acc += hp[k] * reww[k];
    for (int m = 1; m < 64; m <<= 1) acc += __shfl_xor(acc, m, 64);
    if (lane == 0) {
        float g = 0.f;
        const int* sp = sidx + ((size_t)i * BB + b) * LL;
        for (int l = 0; l < 32; ++l) g += reww[1024 + l * 32 + sp[l]];
        pred[rrow] = acc + g + rewb[0];
    }
}

extern "C" void kernel_launch(void* const* d_in, const int* in_sizes, int n_in,
                              void* d_out, int out_size, void* d_ws, size_t ws_size,
                              hipStream_t stream) {
    const float* obs   = (const float*)d_in[0];
    const float* gum   = (const float*)d_in[1];
    const float* ew1   = (const float*)d_in[2];
    const float* eb1   = (const float*)d_in[3];
    const float* ew2   = (const float*)d_in[4];
    const float* eb2   = (const float*)d_in[5];
    const float* wih   = (const float*)d_in[6];
    const float* whh   = (const float*)d_in[7];
    const float* bih   = (const float*)d_in[8];
    const float* bhh   = (const float*)d_in[9];
    const float* priw  = (const float*)d_in[10];
    const float* prib  = (const float*)d_in[11];
    const float* postw = (const float*)d_in[12];
    const float* postb = (const float*)d_in[13];
    const float* dw1   = (const float*)d_in[14];
    const float* db1   = (const float*)d_in[15];
    const float* dw2   = (const float*)d_in[16];
    const float* db2   = (const float*)d_in[17];
    const float* reww  = (const float*)d_in[18];
    const float* rewb  = (const float*)d_in[19];
    const int*   act   = (const int*)d_in[20];
    (void)in_sizes; (void)n_in; (void)out_size; (void)ws_size;

    float* ws = (float*)d_ws;
    float* wihT   = ws;                        // 1042*3072 = 3,201,024
    float* postwT = wihT + 3201024;            // 1024*1024 = 1,048,576
    float* bufA   = postwT + 1048576;          // 8192*1024 : e1 -> epost -> prior_logits
    float* bufB   = bufA + 8388608;            // 8192*1024 : e -> hseq[128][64][1024] -> dec_tmp
    float* plog   = bufB + 8388608;            // 127*64*1024 : post_logits -> gsum
    int*   sidx   = (int*)(plog + 8323072);    // 127*64*32 ints = 260,096
    unsigned int* flags = (unsigned int*)(sidx + 260096);  // 253*256 barrier flags

    float* out = (float*)d_out;
    float* recon = out;                     // 8128*512
    float* pred  = out + 4161536;           // 8128
    float* klo   = pred + 8128;             // 1
    float* hso   = klo + 1;                 // 8128*1024 (NOT 16B-aligned: scalar/AAL=0 paths only)
    float* smo   = hso + 8323072;           // 8128*1024

    hipMemsetAsync(klo, 0, sizeof(float), stream);
    hipMemsetAsync(flags, 0, 253 * 256 * sizeof(unsigned int), stream);

    tr_k<<<dim3(96, 33), dim3(32, 8), 0, stream>>>(wih, wihT);
    tr2_k<<<dim3(32, 32), dim3(32, 8), 0, stream>>>(postw, postwT);
    // encoder
    gemm_k<1,0,1><<<dim3(8, 64), 256, 0, stream>>>(obs,  ew1, bufA, 8192, 1024, 512,  eb1, nullptr);
    gemm_k<1,0,1><<<dim3(8, 64), 256, 0, stream>>>(bufA, ew2, bufB, 8192, 1024, 1024, eb2, nullptr);
    // epost = e @ post_w[1024:] + post_b  (hoisted e-half of posterior logits)
    gemm_k<0,0,1><<<dim3(8, 64), 256, 0, stream>>>(bufB, postw + 1024 * 1024, bufA, 8192, 1024, 1024, postb, nullptr);
    // step-0 sample
    samp0_k<<<64, 256, 0, stream>>>(bufA, gum, smo, sidx);

    // hseq[0] = h0 = zeros (bufB's e-content no longer needed)
    hipMemsetAsync(bufB, 0, 65536 * sizeof(float), stream);

    // persistent scan (127 steps, 2 flag-barriers per step; coop launch for residency)
    {
        float* hseq_p = bufB; float* hso_p = hso;
        const float* wihT_p = wihT; const float* whh_p = whh;
        const float* bih_p = bih; const float* bhh_p = bhh;
        int* sidx_p = sidx; const int* act_p = act;
        const float* postwT_p = postwT; const float* epost_p = bufA;
        const float* gum_p = gum; float* plog_p = plog; float* smo_p = smo;
        unsigned int* flags_p = flags;
        void* args[] = { &hseq_p, &hso_p, &wihT_p, &whh_p, &bih_p, &bhh_p,
                         &sidx_p, &act_p, &postwT_p, &epost_p, &gum_p, &plog_p, &smo_p, &flags_p };
        hipLaunchCooperativeKernel((const void*)scan_k, dim3(256), dim3(512), args, 0, stream);
    }

    // prior logits (A=hso is not 16B-aligned -> AAL=0)
    gemm_k<0,0,0><<<dim3(8, 64), 256, 0, stream>>>(hso, priw, bufA, 8128, 1024, 1024, prib, nullptr);
    // KL
    kl_k<<<8128, 256, 0, stream>>>(bufA, plog, klo);
    // decoder: gather-sum then 2 GEMMs (bufB reused as dec_tmp; hseq dead)
    gsum_k<<<8128, 256, 0, stream>>>(dw1 + 1024 * 1024, sidx, plog);
    gemm_k<1,1,0><<<dim3(8, 64), 256, 0, stream>>>(hso, dw1, bufB, 8128, 1024, 1024, db1, plog);
    gemm_k<0,0,1><<<dim3(4, 64), 256, 0, stream>>>(bufB, dw2, recon, 8128, 512, 1024, db2, nullptr);
    // reward
    rew_k<<<2032, 256, 0, stream>>>(hso, reww, rewb, sidx, pred);
}